// Round 1
// baseline (360.582 us; speedup 1.0000x reference)
//
#include <hip/hip_runtime.h>

// Problem constants (fixed by the reference file)
#define BB 4096
#define FF 16384
#define GG 512
#define SS 32

// Scatter-add w[g,s]*fc[g] into v[idx[g,s]]. General (handles duplicate
// indices); here idx is a permutation of 0..F-1 so no real contention.
__global__ void build_v_kernel(const int* __restrict__ idx,
                               const float* __restrict__ w,
                               const float* __restrict__ fc,
                               float* __restrict__ v) {
    int i = blockIdx.x * blockDim.x + threadIdx.x;
    if (i < GG * SS) {
        int g = i >> 5;  // SS = 32
        atomicAdd(&v[idx[i]], w[i] * fc[g]);
    }
}

// GEMV: out[b] = dot(x[b,:], v).  One 256-thread block per row.
// float4 loads: 16 B/lane, 1 KiB per wave instruction, fully coalesced.
__global__ __launch_bounds__(256) void gemv_kernel(const float* __restrict__ x,
                                                   const float* __restrict__ v,
                                                   float* __restrict__ out) {
    const int b = blockIdx.x;
    const float4* __restrict__ x4 = (const float4*)(x + (size_t)b * FF);
    const float4* __restrict__ v4 = (const float4*)v;

    float sum = 0.0f;
    // FF/4 = 4096 float4 elements over 256 threads -> 16 iters/thread
    #pragma unroll 4
    for (int i = threadIdx.x; i < FF / 4; i += 256) {
        float4 xv = x4[i];
        float4 vv = v4[i];
        sum += xv.x * vv.x + xv.y * vv.y + xv.z * vv.z + xv.w * vv.w;
    }

    // wave(64)-level shuffle reduction
    #pragma unroll
    for (int off = 32; off > 0; off >>= 1)
        sum += __shfl_down(sum, off, 64);

    __shared__ float wsum[4];
    const int wave = threadIdx.x >> 6;
    if ((threadIdx.x & 63) == 0) wsum[wave] = sum;
    __syncthreads();
    if (threadIdx.x == 0)
        out[b] = wsum[0] + wsum[1] + wsum[2] + wsum[3];
}

extern "C" void kernel_launch(void* const* d_in, const int* in_sizes, int n_in,
                              void* d_out, int out_size, void* d_ws, size_t ws_size,
                              hipStream_t stream) {
    const float* x   = (const float*)d_in[0];   // (B, F) fp32
    const int*   idx = (const int*)d_in[1];     // (G, S) int
    const float* w   = (const float*)d_in[2];   // (G, S) fp32
    const float* fc  = (const float*)d_in[3];   // (G, 1) fp32
    float* out = (float*)d_out;                 // (B, 1) fp32
    float* v   = (float*)d_ws;                  // F fp32 scratch (64 KiB)

    // d_ws is re-poisoned to 0xAA before every timed launch -> zero it here.
    hipMemsetAsync(v, 0, FF * sizeof(float), stream);
    build_v_kernel<<<(GG * SS + 255) / 256, 256, 0, stream>>>(idx, w, fc, v);
    gemv_kernel<<<BB, 256, 0, stream>>>(x, v, out);
}

// Round 2
// 337.755 us; speedup vs baseline: 1.0676x; 1.0676x over previous
//
#include <hip/hip_runtime.h>

// Problem constants (fixed by the reference file)
#define BB 4096
#define FF 16384
#define GG 512
#define SS 32

typedef float v4f __attribute__((ext_vector_type(4)));

// Scatter-add w[g,s]*fc[g] into v[idx[g,s]]. General (handles duplicate
// indices); here idx is a permutation of 0..F-1 so no real contention.
__global__ void build_v_kernel(const int* __restrict__ idx,
                               const float* __restrict__ w,
                               const float* __restrict__ fc,
                               float* __restrict__ v) {
    int i = blockIdx.x * blockDim.x + threadIdx.x;
    if (i < GG * SS) {
        int g = i >> 5;  // SS = 32
        atomicAdd(&v[idx[i]], w[i] * fc[g]);
    }
}

// GEMV: out[b] = dot(x[b,:], v).  One 256-thread block per row.
// x is streamed exactly once -> nontemporal loads keep L2 free for v.
__global__ __launch_bounds__(256) void gemv_kernel(const float* __restrict__ x,
                                                   const float* __restrict__ v,
                                                   float* __restrict__ out) {
    const int b = blockIdx.x;
    const v4f* __restrict__ x4 = (const v4f*)(x + (size_t)b * FF);
    const v4f* __restrict__ v4 = (const v4f*)v;

    // 4 independent accumulator lanes (no serial add chain)
    v4f acc = {0.0f, 0.0f, 0.0f, 0.0f};
    // FF/4 = 4096 v4f elements over 256 threads -> 16 iters/thread
    #pragma unroll 8
    for (int i = threadIdx.x; i < FF / 4; i += 256) {
        v4f xv = __builtin_nontemporal_load(&x4[i]);  // streamed, nt
        v4f vv = v4[i];                               // L1/L2-resident
        acc += xv * vv;
    }
    float sum = (acc.x + acc.y) + (acc.z + acc.w);

    // wave(64)-level shuffle reduction
    #pragma unroll
    for (int off = 32; off > 0; off >>= 1)
        sum += __shfl_down(sum, off, 64);

    __shared__ float wsum[4];
    const int wave = threadIdx.x >> 6;
    if ((threadIdx.x & 63) == 0) wsum[wave] = sum;
    __syncthreads();
    if (threadIdx.x == 0)
        out[b] = wsum[0] + wsum[1] + wsum[2] + wsum[3];
}

extern "C" void kernel_launch(void* const* d_in, const int* in_sizes, int n_in,
                              void* d_out, int out_size, void* d_ws, size_t ws_size,
                              hipStream_t stream) {
    const float* x   = (const float*)d_in[0];   // (B, F) fp32
    const int*   idx = (const int*)d_in[1];     // (G, S) int
    const float* w   = (const float*)d_in[2];   // (G, S) fp32
    const float* fc  = (const float*)d_in[3];   // (G, 1) fp32
    float* out = (float*)d_out;                 // (B, 1) fp32
    float* v   = (float*)d_ws;                  // F fp32 scratch (64 KiB)

    // d_ws is re-poisoned to 0xAA before every timed launch -> zero it here.
    hipMemsetAsync(v, 0, FF * sizeof(float), stream);
    build_v_kernel<<<(GG * SS + 255) / 256, 256, 0, stream>>>(idx, w, fc, v);
    gemv_kernel<<<BB, 256, 0, stream>>>(x, v, out);
}